// Round 16
// baseline (41.731 us; speedup 1.0000x reference)
//
#include <hip/hip_runtime.h>

// Problem constants
#define NSPLIT  100
#define MTREE   20
#define MAXLEAF 64
#define EMB     32
#define NTREES  2000
#define BATCH   4096
#define OUTW    (NSPLIT*EMB)             // 3200
#define TAB_F4  (NSPLIT*MTREE*MAXLEAF*8) // 1,024,000 float4 in f32 table
#define SPLIT_B 81920                    // bf16 table bytes per split

#define THREADS 1024
#define CHUNKS  8                        // batch-chunks per split
#define BPC     (BATCH/CHUNKS)           // 512 batches/block, 2 per group
#define NBLK    (NSPLIT*CHUNKS)          // 800

// v16: force the pipeline at ISA level. v15 proved the compiler flattens
// source-level ILP (VGPR_Count=40 with a 128 cap -> 2-3 reads in flight);
// every pipe sits ~25% busy -> latency-bound. Here the 20 gathers per batch
// are asm volatile ds_read_b128 (mutually ordered -> genuinely 16-deep) and
// consumption is gated by counted s_waitcnt lgkmcnt(12/8/4/0) +
// sched_barrier(0) (DS results return in issue order; rule-18 fence keeps
// the dot2s from hoisting above the wait). Peak live ~110 < 128 cap.
// Swizzle reverted (bank class = row parity; intra-row XOR provably void —
// conflict counter identical). dot2 accumulate kept (v15's real gain).
__device__ __forceinline__ unsigned int pk_bf16(float a, float b) {
    unsigned int r;
    asm("v_cvt_pk_bf16_f32 %0, %1, %2" : "=v"(r) : "v"(a), "v"(b));
    return r;
}

__device__ __forceinline__ void stage_dma(const void* gsrc, void* lbase) {
    __builtin_amdgcn_global_load_lds(
        (const __attribute__((address_space(1))) void*)gsrc,
        (__attribute__((address_space(3))) void*)lbase, 16, 0, 0);
}

__device__ __forceinline__ void d2(float& a, unsigned int w, unsigned int sel) {
    asm("v_dot2_f32_bf16 %0, %1, %2, %0" : "+v"(a) : "v"(w), "v"(sel));
}

#define RD1(dst, a, OFF) \
    asm volatile("ds_read_b128 %0, %1 offset:" OFF : "=v"(dst) : "v"(a))
#define LGKM(N) do { \
    asm volatile("s_waitcnt lgkmcnt(" N ")" ::: "memory"); \
    __builtin_amdgcn_sched_barrier(0); } while (0)

// ---- kernel 1: f32 table -> bf16 table in d_ws (row-major, linear) ----
__global__ __launch_bounds__(256) void cvt_tab(
    const float4* __restrict__ src, uint2* __restrict__ dst)
{
    const int i0 = blockIdx.x * 1024 + threadIdx.x;
#pragma unroll
    for (int k = 0; k < 4; ++k) {
        const int i = i0 + k * 256;          // 1000 blocks x 1024 = exact
        const float4 v = src[i];
        dst[i] = make_uint2(pk_bf16(v.x, v.y), pk_bf16(v.z, v.w));
    }
}

// ---- kernel 2: whole-table LDS, ISA-pipelined 16-deep gather ----
__global__ __launch_bounds__(THREADS, 1) void leaf2emb_v16(
    const int* __restrict__ leaves,     // [BATCH, NTREES]
    const char* __restrict__ tab,       // bf16 table in d_ws, row = 64 B
    float* __restrict__ out)            // [BATCH, OUTW]
{
    __shared__ char tl[SPLIT_B];        // 80 KiB: whole split table

    // XCD-chunked swizzle: 800 = 8 x 100.
    const int bid = blockIdx.x;
    const int wkr = (bid & 7) * (NBLK / 8) + (bid >> 3);
    const int s     = wkr >> 3;
    const int chunk = wkr & 7;

    const int tid  = threadIdx.x;
    const int l    = tid & 3;           // lane-in-group: dims [8l, 8l+8)
    const int g    = tid >> 2;          // group id (256 groups, 2 batches each)
    const int w    = tid >> 6;          // wave id
    const int lane = tid & 63;

    const char* gtab = tab + (size_t)s * SPLIT_B;
    {   // stage whole table: 16 waves x 1KB x 5 rounds = 80 KB exact
        const char* gs = gtab + w * 1024 + lane * 16;
        char* lb = tl + w * 1024;
#pragma unroll
        for (int k = 0; k < 5; ++k)
            stage_dma(gs + k * 16384, lb + k * 16384);
    }

    const int bA = chunk * BPC + g;
    const int bB = bA + 256;
    const int4* lvA = (const int4*)(leaves + (size_t)bA * NTREES + s * MTREE);
    const int4* lvB = (const int4*)(leaves + (size_t)bB * NTREES + s * MTREE);

    // both batches' leaves in flight during the staging drain
    int4 L0 = lvA[0], L1 = lvA[1], L2 = lvA[2], L3 = lvA[3], L4 = lvA[4];
    int4 M0 = lvB[0], M1 = lvB[1], M2 = lvB[2], M3 = lvB[3], M4 = lvB[4];

    __syncthreads();                    // the kernel's ONLY barrier

    // 32-bit LDS byte offsets for ds_read operands
    const unsigned tb0 = (unsigned)(uintptr_t)(&tl[0]) + (l << 4);
    const unsigned tbH = tb0 + 65536;   // trees 16..19 window

    const unsigned int selL = 0x00003F80u;   // {hi=0, lo=1.0bf16}
    const unsigned int selH = 0x3F800000u;   // {hi=1.0bf16, lo=0}

#define D2ACC(V) { \
        d2(a0.x, (V).x, selL); d2(a0.y, (V).x, selH); \
        d2(a0.z, (V).y, selL); d2(a0.w, (V).y, selH); \
        d2(a1.x, (V).z, selL); d2(a1.y, (V).z, selH); \
        d2(a1.z, (V).w, selL); d2(a1.w, (V).w, selH); }

    // one batch: 16 reads issued, consume q0, issue last 4, drain by quartets
#define BATCH20(P0, P1, P2, P3, P4) { \
        unsigned qa, qb, qc, qd; \
        qa = tb0 + ((P0).x << 6); qb = tb0 + ((P0).y << 6); \
        qc = tb0 + ((P0).z << 6); qd = tb0 + ((P0).w << 6); \
        RD1(v00, qa, "0");     RD1(v01, qb, "4096"); \
        RD1(v02, qc, "8192");  RD1(v03, qd, "12288"); \
        qa = tb0 + ((P1).x << 6); qb = tb0 + ((P1).y << 6); \
        qc = tb0 + ((P1).z << 6); qd = tb0 + ((P1).w << 6); \
        RD1(v04, qa, "16384"); RD1(v05, qb, "20480"); \
        RD1(v06, qc, "24576"); RD1(v07, qd, "28672"); \
        qa = tb0 + ((P2).x << 6); qb = tb0 + ((P2).y << 6); \
        qc = tb0 + ((P2).z << 6); qd = tb0 + ((P2).w << 6); \
        RD1(v08, qa, "32768"); RD1(v09, qb, "36864"); \
        RD1(v10, qc, "40960"); RD1(v11, qd, "45056"); \
        qa = tb0 + ((P3).x << 6); qb = tb0 + ((P3).y << 6); \
        qc = tb0 + ((P3).z << 6); qd = tb0 + ((P3).w << 6); \
        RD1(v12, qa, "49152"); RD1(v13, qb, "53248"); \
        RD1(v14, qc, "57344"); RD1(v15, qd, "61440"); \
        LGKM("12"); \
        D2ACC(v00) D2ACC(v01) D2ACC(v02) D2ACC(v03) \
        qa = tbH + ((P4).x << 6); qb = tbH + ((P4).y << 6); \
        qc = tbH + ((P4).z << 6); qd = tbH + ((P4).w << 6); \
        RD1(v16, qa, "0");     RD1(v17, qb, "4096"); \
        RD1(v18, qc, "8192");  RD1(v19, qd, "12288"); \
        LGKM("12"); \
        D2ACC(v04) D2ACC(v05) D2ACC(v06) D2ACC(v07) \
        LGKM("8"); \
        D2ACC(v08) D2ACC(v09) D2ACC(v10) D2ACC(v11) \
        LGKM("4"); \
        D2ACC(v12) D2ACC(v13) D2ACC(v14) D2ACC(v15) \
        LGKM("0"); \
        D2ACC(v16) D2ACC(v17) D2ACC(v18) D2ACC(v19) }

    uint4 v00, v01, v02, v03, v04, v05, v06, v07;
    uint4 v08, v09, v10, v11, v12, v13, v14, v15, v16, v17, v18, v19;

    // ---- batch A ----
    float4 a0 = {0,0,0,0}, a1 = {0,0,0,0};
    BATCH20(L0, L1, L2, L3, L4)
    {
        float* oA = out + (size_t)bA * OUTW + s * EMB + l * 8;
        *(float4*)(oA)     = a0;
        *(float4*)(oA + 4) = a1;
    }

    // ---- batch B ----
    a0 = make_float4(0, 0, 0, 0);
    a1 = make_float4(0, 0, 0, 0);
    BATCH20(M0, M1, M2, M3, M4)
    {
        float* oB = out + (size_t)bB * OUTW + s * EMB + l * 8;
        *(float4*)(oB)     = a0;
        *(float4*)(oB + 4) = a1;
    }

#undef D2ACC
#undef BATCH20
}

extern "C" void kernel_launch(void* const* d_in, const int* in_sizes, int n_in,
                              void* d_out, int out_size, void* d_ws, size_t ws_size,
                              hipStream_t stream) {
    const int* leaves  = (const int*)d_in[0];
    const float* embed = (const float*)d_in[1];
    float* out         = (float*)d_out;

    // d_ws: 8.2 MB bf16 table (fully rewritten every call -> deterministic).
    cvt_tab<<<dim3(TAB_F4 / 1024), dim3(256), 0, stream>>>(
        (const float4*)embed, (uint2*)d_ws);

    leaf2emb_v16<<<dim3(NBLK), dim3(THREADS), 0, stream>>>(
        leaves, (const char*)d_ws, out);
}

// Round 17
// 40.666 us; speedup vs baseline: 1.0262x; 1.0262x over previous
//
#include <hip/hip_runtime.h>

// Problem constants
#define NSPLIT  100
#define MTREE   20
#define MAXLEAF 64
#define EMB     32
#define NTREES  2000
#define BATCH   4096
#define OUTW    (NSPLIT*EMB)            // 3200

#define THREADS 1024
#define CHUNKS  8                       // batch-chunks per split
#define BPC     (BATCH/CHUNKS)          // 512 batches/block, 2 per group
#define NBLK    (NSPLIT*CHUNKS)         // 800
#define ROWSTRIDE 80                    // bf16 row (64 B) + 16 B pad: bank
                                        // class = (20r)%32 -> all 8 quad-bank
                                        // classes (5r mod 8), vs 2 at 64 B
#define LDS_B   (MTREE*MAXLEAF*ROWSTRIDE)  // 102400

// v17: fused cvt + padded-stride LDS.
//  Ledger: v7/v12/v14 (different rounds/threads/staging) all ~39.7 -> wall ==
//  gather-loop time; stage/tail hidden. v15 (dot2) = 36.0. Residuals measured:
//  (1) separate cvt kernel ~4.5us serial HBM; (2) 2.149M conflict cycles --
//  64B rows at 64B stride sit on half the banks (row parity), ~8-way pileups;
//  intra-row XOR proven void (counter identical).
//  Fix both: stage f32 table in-kernel (reg -> cvt_pk -> ds_write_b64) at
//  80 B row stride. Reg-staging makes the padded layout legal (no
//  global_load_lds linearity constraint). 16 random rows/wave now spread ~2
//  per bank class -- 2-way is free (m136). No d_ws, single dispatch.
__device__ __forceinline__ unsigned int pk_bf16(float a, float b) {
    unsigned int r;
    asm("v_cvt_pk_bf16_f32 %0, %1, %2" : "=v"(r) : "v"(a), "v"(b));
    return r;
}

// a += 1.0 * (selected bf16 half of w): one VOP3P dot2.
__device__ __forceinline__ void d2(float& a, unsigned int w, unsigned int sel) {
    asm("v_dot2_f32_bf16 %0, %1, %2, %0" : "+v"(a) : "v"(w), "v"(sel));
}

__global__ __launch_bounds__(THREADS, 1) void leaf2emb_v17(
    const int* __restrict__ leaves,     // [BATCH, NTREES]
    const float* __restrict__ embed,    // [NSPLIT, MTREE*MAXLEAF, EMB] f32
    float* __restrict__ out)            // [BATCH, OUTW]
{
    __shared__ char tl[LDS_B];          // 100 KiB: whole split table, 80B rows

    // XCD-chunked swizzle: 800 = 8 x 100 -> a split's 8 blocks share an XCD.
    const int bid = blockIdx.x;
    const int wkr = (bid & 7) * (NBLK / 8) + (bid >> 3);
    const int s     = wkr >> 3;
    const int chunk = wkr & 7;

    const int tid = threadIdx.x;
    const int l   = tid & 3;            // lane-in-group: dims [8l, 8l+8)
    const int g   = tid >> 2;           // group id (256 groups, 2 batches each)

    // ---- fused staging: f32 global -> bf16 LDS @ 80B stride ----
    // i = tid + k*1024 covers 10240 float4; row = i>>3, h = i&7 (4 dims = 8B)
    {
        const float4* emb4 = (const float4*)embed + (size_t)s * 10240;
#pragma unroll 2
        for (int k = 0; k < 10; ++k) {
            const int i = tid + k * 1024;
            const float4 v = emb4[i];
            const int row = i >> 3;
            const int h   = i & 7;
            *(uint2*)(tl + row * ROWSTRIDE + h * 8) =
                make_uint2(pk_bf16(v.x, v.y), pk_bf16(v.z, v.w));
        }
    }

    const int bA = chunk * BPC + g;
    const int bB = bA + 256;
    const int4* lvA = (const int4*)(leaves + (size_t)bA * NTREES + s * MTREE);
    const int4* lvB = (const int4*)(leaves + (size_t)bB * NTREES + s * MTREE);

    // both batches' leaves in flight during the staging tail
    int4 L0 = lvA[0], L1 = lvA[1], L2 = lvA[2], L3 = lvA[3], L4 = lvA[4];
    int4 M0 = lvB[0], M1 = lvB[1], M2 = lvB[2], M3 = lvB[3], M4 = lvB[4];

    __syncthreads();                    // the kernel's ONLY barrier

    // tree t base = t*64*80 = t*5120; split into two bases so the ds offset
    // immediate stays <= 65535 (trees 0..11 off tb, 12..19 off tbH).
    const char* tb  = tl + l * 16;
    const char* tbH = tb + 12 * 5120;

    const unsigned int selL = 0x00003F80u;   // {hi=0, lo=1.0bf16}
    const unsigned int selH = 0x3F800000u;   // {hi=1.0bf16, lo=0}

#define ROW(BASE, TT, LEAF) \
    (*(const uint4*)((BASE) + (TT) * 5120 + (LEAF) * ROWSTRIDE))
#define D2ACC(V) { \
        d2(a0.x, (V).x, selL); d2(a0.y, (V).x, selH); \
        d2(a0.z, (V).y, selL); d2(a0.w, (V).y, selH); \
        d2(a1.x, (V).z, selL); d2(a1.y, (V).z, selH); \
        d2(a1.z, (V).w, selL); d2(a1.w, (V).w, selH); }
#define QUART(BASE, T0, LQ) { \
        uint4 v0 = ROW(BASE, (T0)+0, (LQ).x), v1 = ROW(BASE, (T0)+1, (LQ).y), \
              v2 = ROW(BASE, (T0)+2, (LQ).z), v3 = ROW(BASE, (T0)+3, (LQ).w); \
        D2ACC(v0) D2ACC(v1) D2ACC(v2) D2ACC(v3) }
#define GATHER20(P0, P1, P2, P3, P4) \
        QUART(tb,  0, P0) QUART(tb,  4, P1) QUART(tb,  8, P2) \
        QUART(tbH, 0, P3) QUART(tbH, 4, P4)

    // ---- batch A ----
    float4 a0 = {0,0,0,0}, a1 = {0,0,0,0};
    GATHER20(L0, L1, L2, L3, L4)
    {
        float* oA = out + (size_t)bA * OUTW + s * EMB + l * 8;
        *(float4*)(oA)     = a0;
        *(float4*)(oA + 4) = a1;
    }

    // ---- batch B ----
    a0 = make_float4(0, 0, 0, 0);
    a1 = make_float4(0, 0, 0, 0);
    GATHER20(M0, M1, M2, M3, M4)
    {
        float* oB = out + (size_t)bB * OUTW + s * EMB + l * 8;
        *(float4*)(oB)     = a0;
        *(float4*)(oB + 4) = a1;
    }

#undef ROW
#undef D2ACC
#undef QUART
#undef GATHER20
}

extern "C" void kernel_launch(void* const* d_in, const int* in_sizes, int n_in,
                              void* d_out, int out_size, void* d_ws, size_t ws_size,
                              hipStream_t stream) {
    const int* leaves  = (const int*)d_in[0];
    const float* embed = (const float*)d_in[1];
    float* out         = (float*)d_out;

    leaf2emb_v17<<<dim3(NBLK), dim3(THREADS), 0, stream>>>(leaves, embed, out);
}